// Round 10
// baseline (5166.722 us; speedup 1.0000x reference)
//
#include <hip/hip_runtime.h>
#include <stdint.h>

// PolicyNetRSNNPB R10: wave-autonomous seq-tagged sync.
// R9 (3.69ms): FETCH 0.79GB (PK resident), VALUBusy 36.6%, ~31us/step vs
// ~7us L2-BW floor -> stall = sync coupling (block barriers + flag RMW + 2
// serialized MALL trips). R10 removes ALL in-loop barriers:
//  - m1 chunks carry a seq tag in the same 64B line: [p][smp][xcd][4 mask + seq].
//    Writer: mask stores -> vmcnt(0) -> seq store. Reader wave polls only its
//    2 samples' 16 seq words, then (control-dependent) loads masks.
//  - Per-wave sync with exactly 7 counterpart waves; no syncthreads, no flags.
//    Lap-safe: entering step s requires all producers published m1(s), which
//    happens only after they consumed m1(s-1) -> parity overwrite race-free.
//  - Merged A+B build (half-wave scans), software-pipelined dual gather.
// Bit-exact add order preserved (absmax 0.0 through R9).

typedef unsigned long long u64;
typedef unsigned int u32;
typedef float f32x4 __attribute__((ext_vector_type(4)));

#define NB 512
#define HD 2048
#define NSTEPS 128
#define THREADS 512
#define NBLK 256
#define COLS 256
#define SPB 16
#define NWPS 32
#define LSTN 832

#define DMc 0.8187307530779818f
#define DSc 0.6065306597126334f
#define SMc 0.18126924692201818f

// ---- ws layout ----
#define OFF_M1W 0
#define SZ_M1W ((size_t)2 * NB * 8 * 8 * 8)      // 512 KB: [p][smp][xcd][8 u64]
#define OFF_M2H (OFF_M1W + SZ_M1W)
#define SZ_M2H ((size_t)NSTEPS * NB * NWPS * 8)  // 16 MB
#define OFF_CNT (OFF_M2H + SZ_M2H)
#define OFF_DONE (OFF_CNT + 64)
#define OFF_PK (((size_t)(OFF_DONE + 4) + 4194303) & ~(size_t)4194303)
#define SZ_PK ((size_t)8 * HD * 512 * 4)         // 32 MB

#define HWREG_XCC_ID (20 | ((4 - 1) << 11))

__global__ void init_ws(u64* __restrict__ m1W, u32* __restrict__ cnt,
                        u32* __restrict__ done) {
  int i = blockIdx.x * 256 + threadIdx.x;
  if (i < 2 * NB * 64) m1W[i] = 0ULL;
  if (i < 8) cnt[i] = 0u;
  if (i == 0) *done = 0u;
}

// PK[xcd][k][0..255]=Vr[k][xcd*256+..], [256..511]=Wf[k][..]
__global__ __launch_bounds__(256) void pack_kernel(
    const float* __restrict__ Vr, const float* __restrict__ Wf,
    float* __restrict__ PK) {
  const int k = blockIdx.x;
  const int tid = threadIdx.x;
  for (int c = tid; c < HD; c += 256) {
    int xcd = c >> 8, cc = c & 255;
    size_t base = ((size_t)xcd * HD + k) * 512;
    __builtin_nontemporal_store(Vr[(size_t)k * HD + c], &PK[base + cc]);
    __builtin_nontemporal_store(Wf[(size_t)k * HD + c], &PK[base + 256 + cc]);
  }
}

// bit i of low-16 -> bit 4i
__device__ __forceinline__ u64 spread4(u64 x) {
  x &= 0xffffULL;
  x = (x | (x << 24)) & 0x000000FF000000FFULL;
  x = (x | (x << 12)) & 0x000F000F000F000FULL;
  x = (x | (x << 6))  & 0x0303030303030303ULL;
  x = (x | (x << 3))  & 0x1111111111111111ULL;
  return x;
}

__device__ __forceinline__ u64 pack_word(u64 B0, u64 B1, u64 B2, u64 B3, int q) {
  int sh = q * 16;
  return spread4(B0 >> sh) | (spread4(B1 >> sh) << 1) |
         (spread4(B2 >> sh) << 2) | (spread4(B3 >> sh) << 3);
}

// full-wave list build (readout only; plain loads)
__device__ __forceinline__ int build_list_ro(const u64* __restrict__ mwords,
                                             uint16_t* __restrict__ lstw,
                                             int lane) {
  u64 w = (lane < NWPS) ? mwords[lane] : 0ULL;
  int pc = __popcll(w);
  int pre = pc;
#pragma unroll
  for (int off = 1; off < 64; off <<= 1) {
    int v = __shfl_up(pre, off);
    if (lane >= off) pre += v;
  }
  int excl = pre - pc;
  int total = __shfl(pre, 63);
  int kb = lane << 6;
  while (w) {
    int b = __builtin_ctzll(w);
    w &= w - 1;
    if (excl < LSTN) lstw[excl] = (uint16_t)(kb + b);
    ++excl;
  }
  asm volatile("s_waitcnt lgkmcnt(0)" ::: "memory");
  return total < LSTN ? total : LSTN;
}

__device__ __forceinline__ u32 lif_update(const float acc[4], float syn[4],
                                          float mem[4], u32 snib) {
  u32 nib = 0;
#pragma unroll
  for (int j = 0; j < 4; ++j) {
    float so = (float)((snib >> j) & 1u);
    float nmem = (DMc * mem[j] + SMc * syn[j]) * (1.0f - so);  // R1 shape
    float nsyn = DSc * syn[j] + acc[j];                         // R1 shape
    mem[j] = nmem;
    syn[j] = nsyn;
    if ((nmem - 1.0f) > 0.0f) nib |= (1u << j);
  }
  return nib;
}

// software-pipelined dual gather: ascending k, batch j+1 in flight while
// accumulating batch j. Separate accumulators (bit-exact order).
__device__ __forceinline__ void dual_gather_pipe(const float* __restrict__ PKb,
                                                 const uint16_t* __restrict__ lstw,
                                                 int tot, float aV[4],
                                                 float aW[4]) {
  if (tot <= 0) return;
  f32x4 vaX[8], vbX[8], vaY[8], vbY[8];
#define LOADG(VA, VB, J)                                      \
  {                                                           \
    _Pragma("unroll") for (int u = 0; u < 8; ++u) {           \
      int idx = (J) + u;                                      \
      if (idx >= tot) idx = 0;                                \
      size_t off = ((size_t)lstw[idx]) << 9;                  \
      VA[u] = *(const f32x4*)(PKb + off);                     \
      VB[u] = *(const f32x4*)(PKb + off + 256);               \
    }                                                         \
  }
#define ACCG(VA, VB, J)                                       \
  {                                                           \
    _Pragma("unroll") for (int u = 0; u < 8; ++u)             \
      if ((J) + u < tot) {                                    \
        aV[0] += VA[u].x; aV[1] += VA[u].y;                   \
        aV[2] += VA[u].z; aV[3] += VA[u].w;                   \
        aW[0] += VB[u].x; aW[1] += VB[u].y;                   \
        aW[2] += VB[u].z; aW[3] += VB[u].w;                   \
      }                                                       \
  }
  int j = 0;
  LOADG(vaX, vbX, 0);
  while (true) {
    if (j + 8 < tot) {
      LOADG(vaY, vbY, j + 8);
      ACCG(vaX, vbX, j);
      j += 8;
    } else {
      ACCG(vaX, vbX, j);
      break;
    }
    if (j + 8 < tot) {
      LOADG(vaX, vbX, j + 8);
      ACCG(vaY, vbY, j);
      j += 8;
    } else {
      ACCG(vaY, vbY, j);
      break;
    }
  }
#undef LOADG
#undef ACCG
}

__global__ __launch_bounds__(THREADS, 2) void rsnn_coop(
    const float* __restrict__ state, const float* __restrict__ target,
    const float* __restrict__ Wi, const float* __restrict__ bi,
    const float* __restrict__ Vr, const float* __restrict__ Wf,
    const float* __restrict__ bf, const float* __restrict__ Wo,
    const float* __restrict__ bo, float* __restrict__ out,
    char* __restrict__ wsb) {
  __shared__ float Wi_s[128 * COLS];      // 128 KB
  __shared__ uint16_t lstA_s[8][LSTN];    // 13 KB
  __shared__ uint16_t lstB_s[8][LSTN];    // 13 KB
  __shared__ int sh_xcd, sh_rank;

  u64* m1W = (u64*)(wsb + OFF_M1W);
  u64* m2H = (u64*)(wsb + OFF_M2H);
  u32* cnt = (u32*)(wsb + OFF_CNT);
  u32* done = (u32*)(wsb + OFF_DONE);
  const float* PK = (const float*)(wsb + OFF_PK);

  const int tid = threadIdx.x;
  const int wv = tid >> 6;      // wave = 2 samples
  const int lane = tid & 63;    // lane = 4 columns

  if (tid == 0) {
    int x = __builtin_amdgcn_s_getreg(HWREG_XCC_ID) & 7;
    sh_xcd = x;
    sh_rank = atomicAdd(&cnt[x], 1u) & 31;
  }
  __syncthreads();
  const int xcd = sh_xcd;
  const int g = sh_rank;
  const int c0 = xcd * COLS;
  const int sA = g * SPB + wv * 2, sB = sA + 1;

  // stage Wi column slice into LDS
  for (int i = tid; i < 128 * COLS; i += THREADS) {
    int k = i >> 8, c = i & 255;
    Wi_s[i] = Wi[(size_t)k * HD + c0 + c];
  }

  float bir[4], bfr[4];
#pragma unroll
  for (int j = 0; j < 4; ++j) {
    bir[j] = bi[c0 + lane * 4 + j];
    bfr[j] = bf[c0 + lane * 4 + j];
  }

  float syn1A[4], mem1A[4], syn2A[4], mem2A[4];
  float syn1B[4], mem1B[4], syn2B[4], mem2B[4];
#pragma unroll
  for (int j = 0; j < 4; ++j) {
    syn1A[j] = 0.f; mem1A[j] = 0.f; syn2A[j] = 0.f; mem2A[j] = 0.f;
    syn1B[j] = 0.f; mem1B[j] = 0.f; syn2B[j] = 0.f; mem2B[j] = 0.f;
  }
  u32 nib1A = 0u, nib1B = 0u, nib2A = 0u, nib2B = 0u;
  float xwA[4], xwB[4];

  const float* PKb = PK + (size_t)xcd * HD * 512 + lane * 4;
  uint16_t* lstA = &lstA_s[wv][0];
  uint16_t* lstB = &lstB_s[wv][0];

  __syncthreads();  // Wi_s ready

  // xw(t) for A,B from Wi_s (k-ascending fmaf, bit-exact)
  auto compute_xw = [&](int t2) {
#pragma unroll
    for (int j = 0; j < 4; ++j) { xwA[j] = bir[j]; xwB[j] = bir[j]; }
#pragma unroll
    for (int half = 0; half < 2; ++half) {
      const float* pA = (half ? target : state) + ((size_t)t2 * NB + sA) * 64;
      const float* pB = (half ? target : state) + ((size_t)t2 * NB + sB) * 64;
      for (int q = 0; q < 16; ++q) {
        f32x4 xa = *(const f32x4*)(pA + 4 * q);
        f32x4 xb = *(const f32x4*)(pB + 4 * q);
        float xav[4] = {xa.x, xa.y, xa.z, xa.w};
        float xbv[4] = {xb.x, xb.y, xb.z, xb.w};
#pragma unroll
        for (int kj = 0; kj < 4; ++kj) {
          const f32x4 w4 =
              *(const f32x4*)&Wi_s[(half * 64 + 4 * q + kj) * COLS + lane * 4];
          xwA[0] = fmaf(xav[kj], w4.x, xwA[0]);
          xwA[1] = fmaf(xav[kj], w4.y, xwA[1]);
          xwA[2] = fmaf(xav[kj], w4.z, xwA[2]);
          xwA[3] = fmaf(xav[kj], w4.w, xwA[3]);
          xwB[0] = fmaf(xbv[kj], w4.x, xwB[0]);
          xwB[1] = fmaf(xbv[kj], w4.y, xwB[1]);
          xwB[2] = fmaf(xbv[kj], w4.z, xwB[2]);
          xwB[3] = fmaf(xbv[kj], w4.w, xwB[3]);
        }
      }
    }
  };

  // ---- prologue: xw(0); LIF1(0); publish m1(0) tag 1 into parity-0 buf ----
  compute_xw(0);
  nib1A = lif_update(xwA, syn1A, mem1A, 0u);
  nib1B = lif_update(xwB, syn1B, mem1B, 0u);
  {
    u64 E0 = __ballot(nib1A & 1u), E1 = __ballot(nib1A & 2u);
    u64 E2 = __ballot(nib1A & 4u), E3 = __ballot(nib1A & 8u);
    u64 F0 = __ballot(nib1B & 1u), F1 = __ballot(nib1B & 2u);
    u64 F2 = __ballot(nib1B & 4u), F3 = __ballot(nib1B & 8u);
    if (lane < 4) {
      __hip_atomic_store(&m1W[((size_t)sA * 8 + xcd) * 8 + lane],
                         pack_word(E0, E1, E2, E3, lane), __ATOMIC_RELAXED,
                         __HIP_MEMORY_SCOPE_AGENT);
    } else if (lane < 8) {
      __hip_atomic_store(&m1W[((size_t)sB * 8 + xcd) * 8 + (lane - 4)],
                         pack_word(F0, F1, F2, F3, lane - 4), __ATOMIC_RELAXED,
                         __HIP_MEMORY_SCOPE_AGENT);
    }
    asm volatile("s_waitcnt vmcnt(0)" ::: "memory");
    if (lane < 2) {
      const int smp = lane ? sB : sA;
      __hip_atomic_store(&m1W[((size_t)smp * 8 + xcd) * 8 + 4], (u64)1,
                         __ATOMIC_RELAXED, __HIP_MEMORY_SCOPE_AGENT);
    }
  }

  // ---- main loop: no barriers; per-wave seq-tag sync ----
  for (int s = 0; s < NSTEPS; ++s) {
    u64* m1p = m1W + (size_t)(s & 1) * NB * 64;
    u64* m1n = m1W + (size_t)((s + 1) & 1) * NB * 64;
    const bool last = (s == NSTEPS - 1);

    // 1. poll seq tags for both samples (lanes 0..15), divergent spin
    if (lane < 16) {
      const int smp = (lane < 8) ? sA : sB;
      u64* sp = m1p + ((size_t)smp * 8 + (lane & 7)) * 8 + 4;
      while (__hip_atomic_load(sp, __ATOMIC_RELAXED,
                               __HIP_MEMORY_SCOPE_AGENT) != (u64)(s + 1))
        __builtin_amdgcn_s_sleep(1);
    }

    // 2. mask loads (control-dependent on poll) + half-wave scans + scatter
    int totA, totB;
    {
      const int hf = lane >> 5, wl = lane & 31;
      const int smp2 = hf ? sB : sA;
      u64 w = __hip_atomic_load(
          m1p + ((size_t)smp2 * 8 + (wl >> 2)) * 8 + (wl & 3),
          __ATOMIC_RELAXED, __HIP_MEMORY_SCOPE_AGENT);
      int pc = __popcll(w);
      int pre = pc;
#pragma unroll
      for (int off = 1; off < 32; off <<= 1) {
        int v = __shfl_up(pre, off, 32);
        if (wl >= off) pre += v;
      }
      int excl = pre - pc;
      totA = __shfl(pre, 31);
      totB = __shfl(pre, 63);
      uint16_t* lw = hf ? lstB : lstA;
      int kb = wl << 6;
      while (w) {
        int b = __builtin_ctzll(w);
        w &= w - 1;
        if (excl < LSTN) lw[excl] = (uint16_t)(kb + b);
        ++excl;
      }
      asm volatile("s_waitcnt lgkmcnt(0)" ::: "memory");
      totA = totA < LSTN ? totA : LSTN;
      totB = totB < LSTN ? totB : LSTN;
    }

    // 3. sample A: gather (layer2(s) + layer1(s+1)), LIF, stores
    {
      float aV[4] = {xwA[0], xwA[1], xwA[2], xwA[3]};
      float aW[4] = {bfr[0], bfr[1], bfr[2], bfr[3]};
      dual_gather_pipe(PKb, lstA, totA, aV, aW);
      nib2A = lif_update(aW, syn2A, mem2A, nib2A);
      if (!last) nib1A = lif_update(aV, syn1A, mem1A, nib1A);
      u64 D0 = __ballot(nib2A & 1u), D1 = __ballot(nib2A & 2u);
      u64 D2 = __ballot(nib2A & 4u), D3 = __ballot(nib2A & 8u);
      u64 E0 = __ballot(nib1A & 1u), E1 = __ballot(nib1A & 2u);
      u64 E2 = __ballot(nib1A & 4u), E3 = __ballot(nib1A & 8u);
      if (lane < 4) {
        __hip_atomic_store(&m2H[((size_t)s * NB + sA) * NWPS + 4 * xcd + lane],
                           pack_word(D0, D1, D2, D3, lane), __ATOMIC_RELAXED,
                           __HIP_MEMORY_SCOPE_AGENT);
        if (!last)
          __hip_atomic_store(&m1n[((size_t)sA * 8 + xcd) * 8 + lane],
                             pack_word(E0, E1, E2, E3, lane), __ATOMIC_RELAXED,
                             __HIP_MEMORY_SCOPE_AGENT);
      }
    }

    // 4. sample B
    {
      float aV[4] = {xwB[0], xwB[1], xwB[2], xwB[3]};
      float aW[4] = {bfr[0], bfr[1], bfr[2], bfr[3]};
      dual_gather_pipe(PKb, lstB, totB, aV, aW);
      nib2B = lif_update(aW, syn2B, mem2B, nib2B);
      if (!last) nib1B = lif_update(aV, syn1B, mem1B, nib1B);
      u64 D0 = __ballot(nib2B & 1u), D1 = __ballot(nib2B & 2u);
      u64 D2 = __ballot(nib2B & 4u), D3 = __ballot(nib2B & 8u);
      u64 E0 = __ballot(nib1B & 1u), E1 = __ballot(nib1B & 2u);
      u64 E2 = __ballot(nib1B & 4u), E3 = __ballot(nib1B & 8u);
      if (lane < 4) {
        __hip_atomic_store(&m2H[((size_t)s * NB + sB) * NWPS + 4 * xcd + lane],
                           pack_word(D0, D1, D2, D3, lane), __ATOMIC_RELAXED,
                           __HIP_MEMORY_SCOPE_AGENT);
        if (!last)
          __hip_atomic_store(&m1n[((size_t)sB * 8 + xcd) * 8 + lane],
                             pack_word(E0, E1, E2, E3, lane), __ATOMIC_RELAXED,
                             __HIP_MEMORY_SCOPE_AGENT);
      }
    }

    // 5. drain mask stores, then seq tags (s+2) for both samples
    if (!last) {
      asm volatile("s_waitcnt vmcnt(0)" ::: "memory");
      if (lane < 2) {
        const int smp = lane ? sB : sA;
        __hip_atomic_store(&m1n[((size_t)smp * 8 + xcd) * 8 + 4], (u64)(s + 2),
                           __ATOMIC_RELAXED, __HIP_MEMORY_SCOPE_AGENT);
      }
    }

    // 6. tail: xw for t=(s+2)/2 hidden in siblings' catch-up window
    if (((s & 1) == 0) && (s + 2 < NSTEPS)) compute_xw((s + 2) >> 1);
  }

  // ---- final rendezvous (full fence: flush m2H, inv replay-stale lines) ----
  __syncthreads();
  if (tid == 0) {
    __threadfence();
    __hip_atomic_fetch_add(done, 1u, __ATOMIC_RELEASE, __HIP_MEMORY_SCOPE_AGENT);
    while (__hip_atomic_load(done, __ATOMIC_RELAXED,
                             __HIP_MEMORY_SCOPE_AGENT) < (u32)NBLK)
      __builtin_amdgcn_s_sleep(8);
    __threadfence();
  }
  __syncthreads();

  // ---- deferred readout: 2 waves/block, wave = one sample ----
  if (wv < 2) {
    const int rsmp = blockIdx.x * 2 + wv;
    const float bor = bo[lane];
    float synr = 0.f, memr = 0.f, roprev = 0.f;
    for (int s = 0; s < NSTEPS; ++s) {
      int total = build_list_ro(m2H + ((size_t)s * NB + rsmp) * NWPS, lstA, lane);
      float a = bor;
      for (int j0 = 0; j0 < total; j0 += 8) {
        float vv[8];
#pragma unroll
        for (int u = 0; u < 8; ++u) {
          int idx = j0 + u;
          if (idx >= total) idx = j0;
          vv[u] = Wo[(((size_t)lstA[idx]) << 6) + lane];
        }
#pragma unroll
        for (int u = 0; u < 8; ++u)
          if (j0 + u < total) a += vv[u];
      }
      float nmemr = DMc * memr + SMc * synr;  // R1 shape
      float nsynr = DSc * synr + a;           // R1 shape
      memr = nmemr;
      synr = nsynr;
      if (s & 1) {
        float v = 0.5f * (roprev + nmemr);
        size_t base = ((size_t)(s >> 1) * NB + rsmp) * 32;
        if (lane < 32) out[base + lane] = v;
        else out[(size_t)64 * NB * 32 + base + (lane - 32)] = v;
      } else {
        roprev = nmemr;
      }
    }
  }
}

extern "C" void kernel_launch(void* const* d_in, const int* in_sizes, int n_in,
                              void* d_out, int out_size, void* d_ws, size_t ws_size,
                              hipStream_t stream) {
  const float* state  = (const float*)d_in[0];
  const float* target = (const float*)d_in[1];
  const float* Wi     = (const float*)d_in[2];
  const float* bi     = (const float*)d_in[3];
  const float* Vr     = (const float*)d_in[4];
  const float* Wf     = (const float*)d_in[5];
  const float* bf     = (const float*)d_in[6];
  const float* Wo     = (const float*)d_in[7];
  const float* bo     = (const float*)d_in[8];
  float* out = (float*)d_out;
  char* wsb = (char*)d_ws;

  init_ws<<<256, 256, 0, stream>>>((u64*)(wsb + OFF_M1W), (u32*)(wsb + OFF_CNT),
                                   (u32*)(wsb + OFF_DONE));
  pack_kernel<<<HD, 256, 0, stream>>>(Vr, Wf, (float*)(wsb + OFF_PK));

  void* args[] = {(void*)&state, (void*)&target, (void*)&Wi, (void*)&bi,
                  (void*)&Vr, (void*)&Wf, (void*)&bf, (void*)&Wo, (void*)&bo,
                  (void*)&out, (void*)&wsb};
  (void)hipLaunchCooperativeKernel(rsnn_coop, dim3(NBLK), dim3(THREADS), args, 0,
                                   stream);
}

// Round 11
// 3577.916 us; speedup vs baseline: 1.4441x; 1.4441x over previous
//
#include <hip/hip_runtime.h>
#include <stdint.h>

// PolicyNetRSNNPB R11: R9 sync (best, 3.69ms) + per-step work reduction.
// R10 lesson: distributed seq-tag polling = MALL storm (FETCH 0.79->10.7GB,
// WRITE 5.6GB). Centralized tid0-flag rendezvous stays.
// Changes vs R9:
//  - XW precompute (NT): in-loop xw = one 16B NT load / sample / 2 steps,
//    issued ONE STEP EARLY (zero exposed latency, no L2 pollution).
//    Fallback to R9's Wi_s compute_xw when ws too small.
//  - merged A+B mask build: one atomic round, half-wave scans (-1 MALL RTT).
//  - A+B interleaved gather: 32 loads in flight, halves exposed batch chains.
//  - __launch_bounds__(512,2) VGPR headroom; LDS still pins 1 blk/CU.
// Bit-exact add order preserved (absmax 0.0 through R10).

typedef unsigned long long u64;
typedef unsigned int u32;
typedef float f32x4 __attribute__((ext_vector_type(4)));

#define NB 512
#define HD 2048
#define NSTEPS 128
#define THREADS 512
#define NBLK 256
#define COLS 256
#define SPB 16
#define NWPS 32
#define LSTN 832

#define DMc 0.8187307530779818f
#define DSc 0.6065306597126334f
#define SMc 0.18126924692201818f

// ---- ws layout ----
#define OFF_M1W 0
#define SZ_M1W ((size_t)2 * NB * NWPS * 8)       // 256 KB
#define OFF_M2H (OFF_M1W + SZ_M1W)
#define SZ_M2H ((size_t)NSTEPS * NB * NWPS * 8)  // 16 MB
#define OFF_FLAG (OFF_M2H + SZ_M2H)
#define SZ_FLAG (32 * 32 * 4)
#define OFF_CNT (OFF_FLAG + SZ_FLAG)
#define OFF_DONE (OFF_CNT + 64)
#define OFF_PK (((size_t)(OFF_DONE + 4) + 4194303) & ~(size_t)4194303)
#define SZ_PK ((size_t)8 * HD * 512 * 4)         // 32 MB
#define OFF_XW (((OFF_PK + SZ_PK) + 255) & ~(size_t)255)
#define SZ_XW ((size_t)64 * NB * HD * 4)         // 256 MB

#define HWREG_XCC_ID (20 | ((4 - 1) << 11))

__global__ void init_ws(u64* __restrict__ m1W, u32* __restrict__ flags,
                        u32* __restrict__ cnt, u32* __restrict__ done) {
  int i = blockIdx.x * 256 + threadIdx.x;
  if (i < 2 * NB * NWPS) m1W[i] = 0ULL;
  if (i < 32 * 32) flags[i] = 0u;
  if (i < 8) cnt[i] = 0u;
  if (i == 0) *done = 0u;
}

// PK[xcd][k][0..255]=Vr[k][xcd*256+..], [256..511]=Wf[k][..]
__global__ __launch_bounds__(256) void pack_kernel(
    const float* __restrict__ Vr, const float* __restrict__ Wf,
    float* __restrict__ PK) {
  const int k = blockIdx.x;
  const int tid = threadIdx.x;
  for (int c = tid; c < HD; c += 256) {
    int xcd = c >> 8, cc = c & 255;
    size_t base = ((size_t)xcd * HD + k) * 512;
    __builtin_nontemporal_store(Vr[(size_t)k * HD + c], &PK[base + cc]);
    __builtin_nontemporal_store(Wf[(size_t)k * HD + c], &PK[base + 256 + cc]);
  }
}

// XW[t*NB+n][h] = bi[h] + x(t,n,:) @ Wi  (R1 kernel, NT stores)
__global__ __launch_bounds__(256) void xw_kernel(
    const float* __restrict__ state, const float* __restrict__ target,
    const float* __restrict__ Wi, const float* __restrict__ bi,
    float* __restrict__ XW) {
  __shared__ float xl[16][128];
  const int tid = threadIdx.x;
  const int col = blockIdx.x * 256 + tid;
  const int r0 = blockIdx.y * 16;

  for (int idx = tid; idx < 16 * 128; idx += 256) {
    int r = idx >> 7, k = idx & 127;
    int gg = r0 + r;
    int t = gg >> 9, n = gg & 511;
    float v = (k < 64) ? state[((size_t)(t * NB + n)) * 64 + k]
                       : target[((size_t)(t * NB + n)) * 64 + (k - 64)];
    xl[r][k] = v;
  }
  __syncthreads();

  float acc[16];
  float b = bi[col];
#pragma unroll
  for (int r = 0; r < 16; ++r) acc[r] = b;
  for (int k = 0; k < 128; ++k) {
    float w = Wi[(size_t)k * HD + col];
#pragma unroll
    for (int r = 0; r < 16; ++r) acc[r] = fmaf(xl[r][k], w, acc[r]);
  }
#pragma unroll
  for (int r = 0; r < 16; ++r)
    __builtin_nontemporal_store(acc[r], &XW[(size_t)(r0 + r) * HD + col]);
}

// bit i of low-16 -> bit 4i
__device__ __forceinline__ u64 spread4(u64 x) {
  x &= 0xffffULL;
  x = (x | (x << 24)) & 0x000000FF000000FFULL;
  x = (x | (x << 12)) & 0x000F000F000F000FULL;
  x = (x | (x << 6))  & 0x0303030303030303ULL;
  x = (x | (x << 3))  & 0x1111111111111111ULL;
  return x;
}

__device__ __forceinline__ u64 pack_word(u64 B0, u64 B1, u64 B2, u64 B3, int q) {
  int sh = q * 16;
  return spread4(B0 >> sh) | (spread4(B1 >> sh) << 1) |
         (spread4(B2 >> sh) << 2) | (spread4(B3 >> sh) << 3);
}

// merged A+B list build: lanes 0..31 -> A words, 32..63 -> B (one atomic round)
__device__ __forceinline__ void build_ab(const u64* __restrict__ mA,
                                         const u64* __restrict__ mB,
                                         uint16_t* __restrict__ lstA,
                                         uint16_t* __restrict__ lstB,
                                         int lane, int& totA, int& totB) {
  const int hf = lane >> 5, wl = lane & 31;
  const u64* src = hf ? mB : mA;
  u64 w = __hip_atomic_load(src + wl, __ATOMIC_RELAXED,
                            __HIP_MEMORY_SCOPE_AGENT);
  int pc = __popcll(w);
  int pre = pc;
#pragma unroll
  for (int off = 1; off < 32; off <<= 1) {
    int v = __shfl_up(pre, off, 32);
    if (wl >= off) pre += v;
  }
  int excl = pre - pc;
  totA = __shfl(pre, 31);
  totB = __shfl(pre, 63);
  uint16_t* lw = hf ? lstB : lstA;
  int kb = wl << 6;
  while (w) {
    int b = __builtin_ctzll(w);
    w &= w - 1;
    if (excl < LSTN) lw[excl] = (uint16_t)(kb + b);
    ++excl;
  }
  asm volatile("s_waitcnt lgkmcnt(0)" ::: "memory");
  totA = totA < LSTN ? totA : LSTN;
  totB = totB < LSTN ? totB : LSTN;
}

// full-wave list build (readout only; plain loads)
__device__ __forceinline__ int build_list_ro(const u64* __restrict__ mwords,
                                             uint16_t* __restrict__ lstw,
                                             int lane) {
  u64 w = (lane < NWPS) ? mwords[lane] : 0ULL;
  int pc = __popcll(w);
  int pre = pc;
#pragma unroll
  for (int off = 1; off < 64; off <<= 1) {
    int v = __shfl_up(pre, off);
    if (lane >= off) pre += v;
  }
  int excl = pre - pc;
  int total = __shfl(pre, 63);
  int kb = lane << 6;
  while (w) {
    int b = __builtin_ctzll(w);
    w &= w - 1;
    if (excl < LSTN) lstw[excl] = (uint16_t)(kb + b);
    ++excl;
  }
  asm volatile("s_waitcnt lgkmcnt(0)" ::: "memory");
  return total < LSTN ? total : LSTN;
}

__device__ __forceinline__ u32 lif_update(const float acc[4], float syn[4],
                                          float mem[4], u32 snib) {
  u32 nib = 0;
#pragma unroll
  for (int j = 0; j < 4; ++j) {
    float so = (float)((snib >> j) & 1u);
    float nmem = (DMc * mem[j] + SMc * syn[j]) * (1.0f - so);  // R1 shape
    float nsyn = DSc * syn[j] + acc[j];                         // R1 shape
    mem[j] = nmem;
    syn[j] = nsyn;
    if ((nmem - 1.0f) > 0.0f) nib |= (1u << j);
  }
  return nib;
}

// A+B interleaved dual gather: 32 loads in flight, ascending k per sample,
// separate accumulators (bit-exact).
__device__ __forceinline__ void gather_ab(const float* __restrict__ PKb,
                                          const uint16_t* __restrict__ lstA,
                                          int totA,
                                          const uint16_t* __restrict__ lstB,
                                          int totB, float aVA[4], float aWA[4],
                                          float aVB[4], float aWB[4]) {
  int tot = totA > totB ? totA : totB;
  for (int j0 = 0; j0 < tot; j0 += 8) {
    f32x4 va[8], wa[8], vb[8], wb[8];
#pragma unroll
    for (int u = 0; u < 8; ++u) {
      int ia = j0 + u;
      if (ia >= totA) ia = 0;
      size_t offA = ((size_t)lstA[ia]) << 9;
      va[u] = *(const f32x4*)(PKb + offA);
      wa[u] = *(const f32x4*)(PKb + offA + 256);
    }
#pragma unroll
    for (int u = 0; u < 8; ++u) {
      int ib = j0 + u;
      if (ib >= totB) ib = 0;
      size_t offB = ((size_t)lstB[ib]) << 9;
      vb[u] = *(const f32x4*)(PKb + offB);
      wb[u] = *(const f32x4*)(PKb + offB + 256);
    }
#pragma unroll
    for (int u = 0; u < 8; ++u)
      if (j0 + u < totA) {
        aVA[0] += va[u].x; aVA[1] += va[u].y; aVA[2] += va[u].z; aVA[3] += va[u].w;
        aWA[0] += wa[u].x; aWA[1] += wa[u].y; aWA[2] += wa[u].z; aWA[3] += wa[u].w;
      }
#pragma unroll
    for (int u = 0; u < 8; ++u)
      if (j0 + u < totB) {
        aVB[0] += vb[u].x; aVB[1] += vb[u].y; aVB[2] += vb[u].z; aVB[3] += vb[u].w;
        aWB[0] += wb[u].x; aWB[1] += wb[u].y; aWB[2] += wb[u].z; aWB[3] += wb[u].w;
      }
  }
}

template <int UXW>
__global__ __launch_bounds__(THREADS, 2) void rsnn_coop(
    const float* __restrict__ state, const float* __restrict__ target,
    const float* __restrict__ Wi, const float* __restrict__ bi,
    const float* __restrict__ Vr, const float* __restrict__ Wf,
    const float* __restrict__ bf, const float* __restrict__ Wo,
    const float* __restrict__ bo, float* __restrict__ out,
    char* __restrict__ wsb) {
  __shared__ float Wi_s[128 * COLS];      // 128 KB (fallback xw; pins 1 blk/CU)
  __shared__ uint16_t lstA_s[8][LSTN];    // 13 KB
  __shared__ uint16_t lstB_s[8][LSTN];    // 13 KB
  __shared__ int sh_xcd, sh_rank;

  u64* m1W = (u64*)(wsb + OFF_M1W);
  u64* m2H = (u64*)(wsb + OFF_M2H);
  u32* flags = (u32*)(wsb + OFF_FLAG);
  u32* cnt = (u32*)(wsb + OFF_CNT);
  u32* done = (u32*)(wsb + OFF_DONE);
  const float* PK = (const float*)(wsb + OFF_PK);
  const float* XW = (const float*)(wsb + OFF_XW);

  const int tid = threadIdx.x;
  const int wv = tid >> 6;      // wave = 2 samples
  const int lane = tid & 63;    // lane = 4 columns

  if (tid == 0) {
    int x = __builtin_amdgcn_s_getreg(HWREG_XCC_ID) & 7;
    sh_xcd = x;
    sh_rank = atomicAdd(&cnt[x], 1u) & 31;
  }
  __syncthreads();
  const int xcd = sh_xcd;
  const int g = sh_rank;
  const int c0 = xcd * COLS;
  const int sA = g * SPB + wv * 2, sB = sA + 1;

  if constexpr (!UXW) {
    for (int i = tid; i < 128 * COLS; i += THREADS) {
      int k = i >> 8, c = i & 255;
      Wi_s[i] = Wi[(size_t)k * HD + c0 + c];
    }
  }
  uint16_t* lstA = &lstA_s[wv][0];
  uint16_t* lstB = &lstB_s[wv][0];
  if (lane == 0) { lstA[0] = 0; lstB[0] = 0; }   // guard rows for clamped loads

  float bir[4], bfr[4];
#pragma unroll
  for (int j = 0; j < 4; ++j) {
    bir[j] = bi[c0 + lane * 4 + j];
    bfr[j] = bf[c0 + lane * 4 + j];
  }

  float syn1A[4], mem1A[4], syn2A[4], mem2A[4];
  float syn1B[4], mem1B[4], syn2B[4], mem2B[4];
#pragma unroll
  for (int j = 0; j < 4; ++j) {
    syn1A[j] = 0.f; mem1A[j] = 0.f; syn2A[j] = 0.f; mem2A[j] = 0.f;
    syn1B[j] = 0.f; mem1B[j] = 0.f; syn2B[j] = 0.f; mem2B[j] = 0.f;
  }
  u32 nib1A = 0u, nib1B = 0u, nib2A = 0u, nib2B = 0u;
  float xwA[4], xwB[4];
  f32x4 xwNA, xwNB;

  const float* PKb = PK + (size_t)xcd * HD * 512 + lane * 4;
  const float* XWc = XW + c0 + lane * 4;
  u32* myflag = &flags[g * 32];

  __syncthreads();  // Wi_s / lst guards ready

  // xw(t) for A,B from Wi_s (k-ascending fmaf; fallback only)
  auto compute_xw = [&](int t2) {
#pragma unroll
    for (int j = 0; j < 4; ++j) { xwA[j] = bir[j]; xwB[j] = bir[j]; }
#pragma unroll
    for (int half = 0; half < 2; ++half) {
      const float* pA = (half ? target : state) + ((size_t)t2 * NB + sA) * 64;
      const float* pB = (half ? target : state) + ((size_t)t2 * NB + sB) * 64;
      for (int q = 0; q < 16; ++q) {
        f32x4 xa = *(const f32x4*)(pA + 4 * q);
        f32x4 xb = *(const f32x4*)(pB + 4 * q);
        float xav[4] = {xa.x, xa.y, xa.z, xa.w};
        float xbv[4] = {xb.x, xb.y, xb.z, xb.w};
#pragma unroll
        for (int kj = 0; kj < 4; ++kj) {
          const f32x4 w4 =
              *(const f32x4*)&Wi_s[(half * 64 + 4 * q + kj) * COLS + lane * 4];
          xwA[0] = fmaf(xav[kj], w4.x, xwA[0]);
          xwA[1] = fmaf(xav[kj], w4.y, xwA[1]);
          xwA[2] = fmaf(xav[kj], w4.z, xwA[2]);
          xwA[3] = fmaf(xav[kj], w4.w, xwA[3]);
          xwB[0] = fmaf(xbv[kj], w4.x, xwB[0]);
          xwB[1] = fmaf(xbv[kj], w4.y, xwB[1]);
          xwB[2] = fmaf(xbv[kj], w4.z, xwB[2]);
          xwB[3] = fmaf(xbv[kj], w4.w, xwB[3]);
        }
      }
    }
  };

  // ---- prologue: xw(0); LIF1(0); publish m1(0) into parity-0; rendezvous ----
  if constexpr (UXW) {
    f32x4 a = __builtin_nontemporal_load((const f32x4*)(XWc + (size_t)sA * HD));
    f32x4 b = __builtin_nontemporal_load((const f32x4*)(XWc + (size_t)sB * HD));
    xwA[0] = a.x; xwA[1] = a.y; xwA[2] = a.z; xwA[3] = a.w;
    xwB[0] = b.x; xwB[1] = b.y; xwB[2] = b.z; xwB[3] = b.w;
  } else {
    compute_xw(0);
  }
  nib1A = lif_update(xwA, syn1A, mem1A, 0u);
  nib1B = lif_update(xwB, syn1B, mem1B, 0u);
  {
    u64 E0 = __ballot(nib1A & 1u), E1 = __ballot(nib1A & 2u);
    u64 E2 = __ballot(nib1A & 4u), E3 = __ballot(nib1A & 8u);
    u64 F0 = __ballot(nib1B & 1u), F1 = __ballot(nib1B & 2u);
    u64 F2 = __ballot(nib1B & 4u), F3 = __ballot(nib1B & 8u);
    if (lane < 4)
      __hip_atomic_store(&m1W[(size_t)sA * NWPS + 4 * xcd + lane],
                         pack_word(E0, E1, E2, E3, lane), __ATOMIC_RELAXED,
                         __HIP_MEMORY_SCOPE_AGENT);
    else if (lane < 8)
      __hip_atomic_store(&m1W[(size_t)sB * NWPS + 4 * xcd + (lane - 4)],
                         pack_word(F0, F1, F2, F3, lane - 4), __ATOMIC_RELAXED,
                         __HIP_MEMORY_SCOPE_AGENT);
  }
  // prefetch xw(t=1) one step early
  if constexpr (UXW) {
    xwNA = __builtin_nontemporal_load(
        (const f32x4*)(XWc + ((size_t)1 * NB + sA) * HD));
    xwNB = __builtin_nontemporal_load(
        (const f32x4*)(XWc + ((size_t)1 * NB + sB) * HD));
  }
  __syncthreads();
  if (tid == 0) {
    __hip_atomic_fetch_add(myflag, 1u, __ATOMIC_RELAXED, __HIP_MEMORY_SCOPE_AGENT);
    while (__hip_atomic_load(myflag, __ATOMIC_RELAXED,
                             __HIP_MEMORY_SCOPE_AGENT) < 8u)
      __builtin_amdgcn_s_sleep(2);
  }
  __syncthreads();

  // ---- main loop: step s gathers with m1(s); xw regs hold t=(s+1)>>1 ----
  for (int s = 0; s < NSTEPS; ++s) {
    if (s & 1) {
      // advance xw to t=(s+1)/2
      if constexpr (UXW) {
        xwA[0] = xwNA.x; xwA[1] = xwNA.y; xwA[2] = xwNA.z; xwA[3] = xwNA.w;
        xwB[0] = xwNB.x; xwB[1] = xwNB.y; xwB[2] = xwNB.z; xwB[3] = xwNB.w;
      } else {
        if (s + 1 < NSTEPS) compute_xw((s + 1) >> 1);
      }
    } else {
      // even: issue next xw loads (consumed at s+1)
      if constexpr (UXW) {
        int t2 = (s >> 1) + 1;
        if (t2 < 64) {
          xwNA = __builtin_nontemporal_load(
              (const f32x4*)(XWc + ((size_t)t2 * NB + sA) * HD));
          xwNB = __builtin_nontemporal_load(
              (const f32x4*)(XWc + ((size_t)t2 * NB + sB) * HD));
        }
      }
    }

    const u64* m1cur = m1W + (size_t)(s & 1) * NB * NWPS;
    u64* m1n = m1W + (size_t)((s + 1) & 1) * NB * NWPS;
    const bool last = (s == NSTEPS - 1);

    int totA, totB;
    build_ab(m1cur + (size_t)sA * NWPS, m1cur + (size_t)sB * NWPS, lstA, lstB,
             lane, totA, totB);

    float aVA[4] = {xwA[0], xwA[1], xwA[2], xwA[3]};
    float aWA[4] = {bfr[0], bfr[1], bfr[2], bfr[3]};
    float aVB[4] = {xwB[0], xwB[1], xwB[2], xwB[3]};
    float aWB[4] = {bfr[0], bfr[1], bfr[2], bfr[3]};
    gather_ab(PKb, lstA, totA, lstB, totB, aVA, aWA, aVB, aWB);

    // LIF2(s) -> m2 history; LIF1(s+1) -> next m1 buffer
    nib2A = lif_update(aWA, syn2A, mem2A, nib2A);
    nib2B = lif_update(aWB, syn2B, mem2B, nib2B);
    if (!last) {
      nib1A = lif_update(aVA, syn1A, mem1A, nib1A);
      nib1B = lif_update(aVB, syn1B, mem1B, nib1B);
    }
    {
      u64 D0 = __ballot(nib2A & 1u), D1 = __ballot(nib2A & 2u);
      u64 D2 = __ballot(nib2A & 4u), D3 = __ballot(nib2A & 8u);
      u64 G0 = __ballot(nib2B & 1u), G1 = __ballot(nib2B & 2u);
      u64 G2 = __ballot(nib2B & 4u), G3 = __ballot(nib2B & 8u);
      if (lane < 4)
        __hip_atomic_store(&m2H[((size_t)s * NB + sA) * NWPS + 4 * xcd + lane],
                           pack_word(D0, D1, D2, D3, lane), __ATOMIC_RELAXED,
                           __HIP_MEMORY_SCOPE_AGENT);
      else if (lane < 8)
        __hip_atomic_store(
            &m2H[((size_t)s * NB + sB) * NWPS + 4 * xcd + (lane - 4)],
            pack_word(G0, G1, G2, G3, lane - 4), __ATOMIC_RELAXED,
            __HIP_MEMORY_SCOPE_AGENT);
      if (!last) {
        u64 E0 = __ballot(nib1A & 1u), E1 = __ballot(nib1A & 2u);
        u64 E2 = __ballot(nib1A & 4u), E3 = __ballot(nib1A & 8u);
        u64 F0 = __ballot(nib1B & 1u), F1 = __ballot(nib1B & 2u);
        u64 F2 = __ballot(nib1B & 4u), F3 = __ballot(nib1B & 8u);
        if (lane < 4)
          __hip_atomic_store(&m1n[(size_t)sA * NWPS + 4 * xcd + lane],
                             pack_word(E0, E1, E2, E3, lane), __ATOMIC_RELAXED,
                             __HIP_MEMORY_SCOPE_AGENT);
        else if (lane < 8)
          __hip_atomic_store(&m1n[(size_t)sB * NWPS + 4 * xcd + (lane - 4)],
                             pack_word(F0, F1, F2, F3, lane - 4),
                             __ATOMIC_RELAXED, __HIP_MEMORY_SCOPE_AGENT);
      }
    }

    if (!last) {
      __syncthreads();
      if (tid == 0) {
        __hip_atomic_fetch_add(myflag, 1u, __ATOMIC_RELAXED,
                               __HIP_MEMORY_SCOPE_AGENT);
        u32 tgt = 8u * (u32)(s + 2);
        while (__hip_atomic_load(myflag, __ATOMIC_RELAXED,
                                 __HIP_MEMORY_SCOPE_AGENT) < tgt)
          __builtin_amdgcn_s_sleep(2);
      }
      __syncthreads();
    }
  }

  // ---- final rendezvous (full fence once: flush + replay-stale inv) ----
  __syncthreads();
  if (tid == 0) {
    __threadfence();
    __hip_atomic_fetch_add(done, 1u, __ATOMIC_RELEASE, __HIP_MEMORY_SCOPE_AGENT);
    while (__hip_atomic_load(done, __ATOMIC_RELAXED,
                             __HIP_MEMORY_SCOPE_AGENT) < (u32)NBLK)
      __builtin_amdgcn_s_sleep(8);
    __threadfence();
  }
  __syncthreads();

  // ---- deferred readout: 2 waves/block, wave = one sample ----
  if (wv < 2) {
    const int rsmp = blockIdx.x * 2 + wv;
    const float bor = bo[lane];
    float synr = 0.f, memr = 0.f, roprev = 0.f;
    for (int s = 0; s < NSTEPS; ++s) {
      int total = build_list_ro(m2H + ((size_t)s * NB + rsmp) * NWPS, lstA, lane);
      float a = bor;
      for (int j0 = 0; j0 < total; j0 += 8) {
        float vv[8];
#pragma unroll
        for (int u = 0; u < 8; ++u) {
          int idx = j0 + u;
          if (idx >= total) idx = j0;
          vv[u] = Wo[(((size_t)lstA[idx]) << 6) + lane];
        }
#pragma unroll
        for (int u = 0; u < 8; ++u)
          if (j0 + u < total) a += vv[u];
      }
      float nmemr = DMc * memr + SMc * synr;  // R1 shape
      float nsynr = DSc * synr + a;           // R1 shape
      memr = nmemr;
      synr = nsynr;
      if (s & 1) {
        float v = 0.5f * (roprev + nmemr);
        size_t base = ((size_t)(s >> 1) * NB + rsmp) * 32;
        if (lane < 32) out[base + lane] = v;
        else out[(size_t)64 * NB * 32 + base + (lane - 32)] = v;
      } else {
        roprev = nmemr;
      }
    }
  }
}

extern "C" void kernel_launch(void* const* d_in, const int* in_sizes, int n_in,
                              void* d_out, int out_size, void* d_ws, size_t ws_size,
                              hipStream_t stream) {
  const float* state  = (const float*)d_in[0];
  const float* target = (const float*)d_in[1];
  const float* Wi     = (const float*)d_in[2];
  const float* bi     = (const float*)d_in[3];
  const float* Vr     = (const float*)d_in[4];
  const float* Wf     = (const float*)d_in[5];
  const float* bf     = (const float*)d_in[6];
  const float* Wo     = (const float*)d_in[7];
  const float* bo     = (const float*)d_in[8];
  float* out = (float*)d_out;
  char* wsb = (char*)d_ws;

  const int use_xw = (ws_size >= OFF_XW + SZ_XW) ? 1 : 0;

  init_ws<<<128, 256, 0, stream>>>((u64*)(wsb + OFF_M1W), (u32*)(wsb + OFF_FLAG),
                                   (u32*)(wsb + OFF_CNT), (u32*)(wsb + OFF_DONE));
  pack_kernel<<<HD, 256, 0, stream>>>(Vr, Wf, (float*)(wsb + OFF_PK));
  if (use_xw)
    xw_kernel<<<dim3(8, 2048), 256, 0, stream>>>(state, target, Wi, bi,
                                                 (float*)(wsb + OFF_XW));

  void* args[] = {(void*)&state, (void*)&target, (void*)&Wi, (void*)&bi,
                  (void*)&Vr, (void*)&Wf, (void*)&bf, (void*)&Wo, (void*)&bo,
                  (void*)&out, (void*)&wsb};
  if (use_xw)
    (void)hipLaunchCooperativeKernel(rsnn_coop<1>, dim3(NBLK), dim3(THREADS),
                                     args, 0, stream);
  else
    (void)hipLaunchCooperativeKernel(rsnn_coop<0>, dim3(NBLK), dim3(THREADS),
                                     args, 0, stream);
}